// Round 1
// baseline (86.316 us; speedup 1.0000x reference)
//
#include <hip/hip_runtime.h>
#include <math.h>

#define NPTS 50000
#define KNBR 16
#define LAT  16
#define NCLS 64
#define NB   4

__device__ __forceinline__ float sigmoidf_(float v) { return 1.0f / (1.0f + expf(-v)); }

// ---------------- Kernel 1: x @ enc1_w.T partials ----------------
// grid = 200 rows * 4 chunks; block 256. part[j*16 + chunk*4 + b]
__global__ __launch_bounds__(256) void k_enc1(const float* __restrict__ x,
                                              const float* __restrict__ w,
                                              float* __restrict__ part) {
  const int NV4 = NPTS / 4;   // 12500 float4 per row
  const int CV  = NV4 / 4;    // 3125 float4 per chunk
  int j = blockIdx.x >> 2;
  int chunk = blockIdx.x & 3;
  int t = threadIdx.x;
  const float4* wv = (const float4*)(w + (size_t)j * NPTS);
  const float4* xv = (const float4*)x;
  float a0 = 0.f, a1 = 0.f, a2 = 0.f, a3 = 0.f;
  int vend = (chunk + 1) * CV;
  for (int v = chunk * CV + t; v < vend; v += 256) {
    float4 wf = wv[v];
    float4 x0 = xv[v];
    float4 x1 = xv[NV4 + v];
    float4 x2 = xv[2 * NV4 + v];
    float4 x3 = xv[3 * NV4 + v];
    a0 += wf.x * x0.x + wf.y * x0.y + wf.z * x0.z + wf.w * x0.w;
    a1 += wf.x * x1.x + wf.y * x1.y + wf.z * x1.z + wf.w * x1.w;
    a2 += wf.x * x2.x + wf.y * x2.y + wf.z * x2.z + wf.w * x2.w;
    a3 += wf.x * x3.x + wf.y * x3.y + wf.z * x3.z + wf.w * x3.w;
  }
#pragma unroll
  for (int off = 32; off > 0; off >>= 1) {
    a0 += __shfl_down(a0, off);
    a1 += __shfl_down(a1, off);
    a2 += __shfl_down(a2, off);
    a3 += __shfl_down(a3, off);
  }
  __shared__ float red[4][4];
  int wid = t >> 6;
  if ((t & 63) == 0) {
    red[wid][0] = a0; red[wid][1] = a1; red[wid][2] = a2; red[wid][3] = a3;
  }
  __syncthreads();
  if (t < 4) {
    float s = red[0][t] + red[1][t] + red[2][t] + red[3][t];
    part[j * 16 + chunk * 4 + t] = s;
  }
}

// ---------------- Kernel 2: tiny MLP chain (one block) ----------------
__global__ __launch_bounds__(512) void k_mlp(const float* __restrict__ part,
                                             const float* __restrict__ enc1_b,
                                             const float* __restrict__ enc2_w,
                                             const float* __restrict__ enc2_b,
                                             const float* __restrict__ h0_w,
                                             const float* __restrict__ h0_b,
                                             const float* __restrict__ h1_w,
                                             const float* __restrict__ h1_b,
                                             const float* __restrict__ h2_w,
                                             const float* __restrict__ h2_b,
                                             float* __restrict__ w_enc,
                                             float* __restrict__ w_hcl) {
  __shared__ float s_h[NB][200];
  __shared__ float s_enc[NB][LAT];
  __shared__ float s_z0[NB][200];
  __shared__ float s_z1[NB][200];
  int t = threadIdx.x;

  // Stage A: h = sigmoid(sum of 4 chunk partials + bias)
  for (int o = t; o < 800; o += 512) {
    int j = o >> 2, b = o & 3;
    float v = part[j * 16 + 0 + b] + part[j * 16 + 4 + b] +
              part[j * 16 + 8 + b] + part[j * 16 + 12 + b] + enc1_b[j];
    s_h[b][j] = sigmoidf_(v);
  }
  __syncthreads();

  // Stage B: encoded = h @ enc2_w.T + enc2_b   (4x16)
  if (t < NB * LAT) {
    int b = t >> 4, i = t & 15;
    float s = enc2_b[i];
    for (int j = 0; j < 200; ++j) s += s_h[b][j] * enc2_w[i * 200 + j];
    s_enc[b][i] = s;
    w_enc[b * LAT + i] = s;
  }
  __syncthreads();

  // Stage C: z0 = swish(encoded @ h0_w.T + h0_b)   (4x200)
  for (int o = t; o < 800; o += 512) {
    int jo = o >> 2, b = o & 3;
    float s = h0_b[jo];
#pragma unroll
    for (int i = 0; i < LAT; ++i) s += s_enc[b][i] * h0_w[jo * LAT + i];
    s_z0[b][jo] = s * sigmoidf_(s);
  }
  __syncthreads();

  // Stage D: z1 = swish(z0 @ h1_w.T + h1_b)   (4x200)
  for (int o = t; o < 800; o += 512) {
    int jo = o >> 2, b = o & 3;
    float s = h1_b[jo];
    for (int j = 0; j < 200; ++j) s += s_z0[b][j] * h1_w[jo * 200 + j];
    s_z1[b][jo] = s * sigmoidf_(s);
  }
  __syncthreads();

  // Stage E: H_cluster = sigmoid(0.01 * (z1 @ h2_w.T + h2_b))   (4x64)
  for (int o = t; o < NB * NCLS; o += 512) {
    int c = o >> 2, b = o & 3;
    float s = h2_b[c];
    for (int j = 0; j < 200; ++j) s += s_z1[b][j] * h2_w[c * 200 + j];
    w_hcl[b * NCLS + c] = sigmoidf_(0.01f * s);
  }
}

// ---------------- Kernel 3: neighbour convolution + output ----------------
// block 256 = 4 waves; wave w handles batch b=w, lanes cover 64 consecutive n.
__global__ __launch_bounds__(256) void k_conv(const int* __restrict__ nid,
                                              const float* __restrict__ nd,
                                              const int* __restrict__ labels,
                                              const float* __restrict__ dec_w,
                                              const float* __restrict__ dec_b,
                                              const float* __restrict__ Bp,
                                              const float* __restrict__ w_enc,
                                              const float* __restrict__ w_hcl,
                                              float* __restrict__ out) {
  __shared__ float s_enc[NB * LAT];
  __shared__ float s_hcl[NB * NCLS];
  int t = threadIdx.x;
  if (t < NB * LAT) s_enc[t] = w_enc[t];
  s_hcl[t] = w_hcl[t];
  __syncthreads();

  int b = t >> 6;
  int n = blockIdx.x * 64 + (t & 63);
  if (n >= NPTS) return;

  float Bv = Bp[0];
  int lab = labels[n];
  float H = s_hcl[b * NCLS + lab];
  float base = 1.0f - 0.5f * H;
  float rbase2 = 1.0f / (base * base);
  float inv0 = 1.0f / (4.0f * Bv * Bv);

  float d2[KNBR];
  int nbr[KNBR];
  const float4* ndv = (const float4*)(nd + (size_t)n * KNBR);
  const int4* niv = (const int4*)(nid + (size_t)n * KNBR);
#pragma unroll
  for (int q = 0; q < 4; ++q) {
    float4 v = ndv[q];
    d2[4 * q + 0] = v.x * v.x; d2[4 * q + 1] = v.y * v.y;
    d2[4 * q + 2] = v.z * v.z; d2[4 * q + 3] = v.w * v.w;
    int4 iv = niv[q];
    nbr[4 * q + 0] = iv.x; nbr[4 * q + 1] = iv.y;
    nbr[4 * q + 2] = iv.z; nbr[4 * q + 3] = iv.w;
  }

  // Pass 1: per-latent normalization sums; cache invden[i]
  float invden[LAT];
  float coef[LAT];
  float ivd = inv0;
#pragma unroll
  for (int i = 0; i < LAT; ++i) {
    invden[i] = ivd;
    float s = 0.f;
#pragma unroll
    for (int k = 0; k < KNBR; ++k) {
      float win = fmaxf(fmaf(-d2[k], ivd, 1.0f), 0.0f);
      s += win;
    }
    coef[i] = s_enc[b * LAT + i] / s;   // s >= 1 (k=0 term is exactly 1)
    ivd *= rbase2;
  }

  // Pass 2: gather dec_w rows, accumulate output
  float acc0 = 0.f, acc1 = 0.f, acc2 = 0.f, acc3 = 0.f;
#pragma unroll
  for (int k = 0; k < KNBR; ++k) {
    const float4* dv = (const float4*)(dec_w + (size_t)nbr[k] * LAT);
    float4 w0 = dv[0], w1 = dv[1], w2 = dv[2], w3 = dv[3];
    float dw[LAT] = {w0.x, w0.y, w0.z, w0.w, w1.x, w1.y, w1.z, w1.w,
                     w2.x, w2.y, w2.z, w2.w, w3.x, w3.y, w3.z, w3.w};
    float a = 0.f;
#pragma unroll
    for (int i = 0; i < LAT; ++i) {
      float win = fmaxf(fmaf(-d2[k], invden[i], 1.0f), 0.0f);
      a = fmaf(coef[i] * win, dw[i], a);
    }
    if ((k & 3) == 0) acc0 += a;
    else if ((k & 3) == 1) acc1 += a;
    else if ((k & 3) == 2) acc2 += a;
    else acc3 += a;
  }
  out[(size_t)b * NPTS + n] = acc0 + acc1 + acc2 + acc3 + dec_b[n];
}

extern "C" void kernel_launch(void* const* d_in, const int* in_sizes, int n_in,
                              void* d_out, int out_size, void* d_ws, size_t ws_size,
                              hipStream_t stream) {
  const float* x      = (const float*)d_in[0];
  const int*   nid    = (const int*)d_in[1];
  const float* nd     = (const float*)d_in[2];
  const int*   labels = (const int*)d_in[3];
  const float* enc1_w = (const float*)d_in[4];
  const float* enc1_b = (const float*)d_in[5];
  const float* enc2_w = (const float*)d_in[6];
  const float* enc2_b = (const float*)d_in[7];
  const float* dec_w  = (const float*)d_in[8];
  const float* dec_b  = (const float*)d_in[9];
  const float* h0_w   = (const float*)d_in[10];
  const float* h0_b   = (const float*)d_in[11];
  const float* h1_w   = (const float*)d_in[12];
  const float* h1_b   = (const float*)d_in[13];
  const float* h2_w   = (const float*)d_in[14];
  const float* h2_b   = (const float*)d_in[15];
  const float* Bp     = (const float*)d_in[16];
  float* out = (float*)d_out;
  float* ws  = (float*)d_ws;
  float* part  = ws;          // 200*16 = 3200 floats
  float* w_enc = ws + 3200;   // 64 floats
  float* w_hcl = ws + 3264;   // 256 floats

  k_enc1<<<800, 256, 0, stream>>>(x, enc1_w, part);
  k_mlp<<<1, 512, 0, stream>>>(part, enc1_b, enc2_w, enc2_b, h0_w, h0_b,
                               h1_w, h1_b, h2_w, h2_b, w_enc, w_hcl);
  k_conv<<<(NPTS + 63) / 64, 256, 0, stream>>>(nid, nd, labels, dec_w, dec_b,
                                               Bp, w_enc, w_hcl, out);
}

// Round 2
// 60.497 us; speedup vs baseline: 1.4268x; 1.4268x over previous
//
#include <hip/hip_runtime.h>
#include <math.h>

#define NPTS 50000
#define KNBR 16
#define LAT  16
#define NCLS 64
#define NB   4

__device__ __forceinline__ float sigmoidf_(float v) { return 1.0f / (1.0f + expf(-v)); }

// ---------------- Kernel 1: x @ enc1_w.T partials ----------------
// grid = 200 rows * 4 chunks; block 256. part[j*16 + chunk*4 + b]
__global__ __launch_bounds__(256) void k_enc1(const float* __restrict__ x,
                                              const float* __restrict__ w,
                                              float* __restrict__ part) {
  const int NV4 = NPTS / 4;   // 12500 float4 per row
  const int CV  = NV4 / 4;    // 3125 float4 per chunk
  int j = blockIdx.x >> 2;
  int chunk = blockIdx.x & 3;
  int t = threadIdx.x;
  const float4* wv = (const float4*)(w + (size_t)j * NPTS);
  const float4* xv = (const float4*)x;
  float a0 = 0.f, a1 = 0.f, a2 = 0.f, a3 = 0.f;
  int vend = (chunk + 1) * CV;
  for (int v = chunk * CV + t; v < vend; v += 256) {
    float4 wf = wv[v];
    float4 x0 = xv[v];
    float4 x1 = xv[NV4 + v];
    float4 x2 = xv[2 * NV4 + v];
    float4 x3 = xv[3 * NV4 + v];
    a0 += wf.x * x0.x + wf.y * x0.y + wf.z * x0.z + wf.w * x0.w;
    a1 += wf.x * x1.x + wf.y * x1.y + wf.z * x1.z + wf.w * x1.w;
    a2 += wf.x * x2.x + wf.y * x2.y + wf.z * x2.z + wf.w * x2.w;
    a3 += wf.x * x3.x + wf.y * x3.y + wf.z * x3.z + wf.w * x3.w;
  }
#pragma unroll
  for (int off = 32; off > 0; off >>= 1) {
    a0 += __shfl_down(a0, off);
    a1 += __shfl_down(a1, off);
    a2 += __shfl_down(a2, off);
    a3 += __shfl_down(a3, off);
  }
  __shared__ float red[4][4];
  int wid = t >> 6;
  if ((t & 63) == 0) {
    red[wid][0] = a0; red[wid][1] = a1; red[wid][2] = a2; red[wid][3] = a3;
  }
  __syncthreads();
  if (t < 4) {
    float s = red[0][t] + red[1][t] + red[2][t] + red[3][t];
    part[j * 16 + chunk * 4 + t] = s;
  }
}

// ---------------- Kernel 2: tiny MLP chain (one block, 512 thr) ----------------
__global__ __launch_bounds__(512) void k_mlp(const float* __restrict__ part,
                                             const float* __restrict__ enc1_b,
                                             const float* __restrict__ enc2_w,
                                             const float* __restrict__ enc2_b,
                                             const float* __restrict__ h0_w,
                                             const float* __restrict__ h0_b,
                                             const float* __restrict__ h1_w,
                                             const float* __restrict__ h1_b,
                                             const float* __restrict__ h2_w,
                                             const float* __restrict__ h2_b,
                                             float* __restrict__ w_enc,
                                             float* __restrict__ w_hcl) {
  __shared__ float s_h[NB][200];
  __shared__ float s_enc[NB][LAT];
  __shared__ __align__(16) float s_z0t[200][NB];   // [j][b]
  __shared__ __align__(16) float s_z1t[200][NB];   // [j][b]
  int t = threadIdx.x;

  // ---- A: h = sigmoid(sum of 4 chunk partials + bias) ----
  for (int o = t; o < 800; o += 512) {
    int j = o >> 2, b = o & 3;
    float v = part[j * 16 + 0 + b] + part[j * 16 + 4 + b] +
              part[j * 16 + 8 + b] + part[j * 16 + 12 + b] + enc1_b[j];
    s_h[b][j] = sigmoidf_(v);
  }
  __syncthreads();

  // ---- B: encoded = h @ enc2_w.T + enc2_b  (64 outputs x 8 lanes) ----
  {
    int out_id = t >> 3, p = t & 7;
    int b = out_id >> 4, i = out_id & 15;
    const float4* w4 = (const float4*)(enc2_w + i * 200);
    float s = 0.f;
    for (int f = p; f < 50; f += 8) {
      float4 w = w4[f];
      int j = f * 4;
      s += w.x * s_h[b][j] + w.y * s_h[b][j + 1] + w.z * s_h[b][j + 2] + w.w * s_h[b][j + 3];
    }
    s += __shfl_down(s, 4, 8);
    s += __shfl_down(s, 2, 8);
    s += __shfl_down(s, 1, 8);
    if (p == 0) {
      s += enc2_b[i];
      s_enc[b][i] = s;
      w_enc[b * LAT + i] = s;
    }
  }
  __syncthreads();

  // ---- C: z0 = swish(encoded @ h0_w.T + h0_b)  (800 outputs) ----
  for (int o = t; o < 800; o += 512) {
    int jo = o >> 2, b = o & 3;
    const float4* hw = (const float4*)(h0_w + jo * LAT);
    float4 w0 = hw[0], w1 = hw[1], w2 = hw[2], w3 = hw[3];
    float s = h0_b[jo];
    s += w0.x * s_enc[b][0] + w0.y * s_enc[b][1] + w0.z * s_enc[b][2] + w0.w * s_enc[b][3];
    s += w1.x * s_enc[b][4] + w1.y * s_enc[b][5] + w1.z * s_enc[b][6] + w1.w * s_enc[b][7];
    s += w2.x * s_enc[b][8] + w2.y * s_enc[b][9] + w2.z * s_enc[b][10] + w2.w * s_enc[b][11];
    s += w3.x * s_enc[b][12] + w3.y * s_enc[b][13] + w3.z * s_enc[b][14] + w3.w * s_enc[b][15];
    s_z0t[jo][b] = s * sigmoidf_(s);
  }
  __syncthreads();

  // ---- D: z1 = swish(z0 @ h1_w.T + h1_b)  (400 thr: 100 groups x 4 lanes, 2 rows each) ----
  if (t < 400) {
    int g = t >> 2, q = t & 3;       // rows g and g+100
    const float4* w4 = (const float4*)h1_w;
    float dacc[8];
#pragma unroll
    for (int a = 0; a < 8; ++a) dacc[a] = 0.f;
    for (int c = 0; c < 13; ++c) {
      int j4 = c * 4 + q;
      if (j4 < 50) {
        float4 wa = w4[g * 50 + j4];
        float4 wb = w4[(g + 100) * 50 + j4];
        int j = j4 * 4;
        float4 z0 = *(const float4*)&s_z0t[j][0];
        float4 z1 = *(const float4*)&s_z0t[j + 1][0];
        float4 z2 = *(const float4*)&s_z0t[j + 2][0];
        float4 z3 = *(const float4*)&s_z0t[j + 3][0];
        dacc[0] += wa.x * z0.x + wa.y * z1.x + wa.z * z2.x + wa.w * z3.x;
        dacc[1] += wa.x * z0.y + wa.y * z1.y + wa.z * z2.y + wa.w * z3.y;
        dacc[2] += wa.x * z0.z + wa.y * z1.z + wa.z * z2.z + wa.w * z3.z;
        dacc[3] += wa.x * z0.w + wa.y * z1.w + wa.z * z2.w + wa.w * z3.w;
        dacc[4] += wb.x * z0.x + wb.y * z1.x + wb.z * z2.x + wb.w * z3.x;
        dacc[5] += wb.x * z0.y + wb.y * z1.y + wb.z * z2.y + wb.w * z3.y;
        dacc[6] += wb.x * z0.z + wb.y * z1.z + wb.z * z2.z + wb.w * z3.z;
        dacc[7] += wb.x * z0.w + wb.y * z1.w + wb.z * z2.w + wb.w * z3.w;
      }
    }
#pragma unroll
    for (int a = 0; a < 8; ++a) {
      dacc[a] += __shfl_xor(dacc[a], 1, 4);
      dacc[a] += __shfl_xor(dacc[a], 2, 4);
    }
    if (q == 0) {
      float ba = h1_b[g], bb = h1_b[g + 100];
#pragma unroll
      for (int b = 0; b < 4; ++b) {
        float sa = dacc[b] + ba;
        float sb = dacc[4 + b] + bb;
        s_z1t[g][b] = sa * sigmoidf_(sa);
        s_z1t[g + 100][b] = sb * sigmoidf_(sb);
      }
    }
  }
  __syncthreads();

  // ---- E: H_cluster = sigmoid(0.01*(z1 @ h2_w.T + h2_b))  (64 c x 8 lanes, all 4 b) ----
  {
    int c = t >> 3, p = t & 7;
    const float4* w4 = (const float4*)(h2_w + c * 200);
    float e0 = 0.f, e1 = 0.f, e2 = 0.f, e3 = 0.f;
    for (int f = p; f < 50; f += 8) {
      float4 w = w4[f];
      int j = f * 4;
      float4 za = *(const float4*)&s_z1t[j][0];
      float4 zb = *(const float4*)&s_z1t[j + 1][0];
      float4 zc = *(const float4*)&s_z1t[j + 2][0];
      float4 zd = *(const float4*)&s_z1t[j + 3][0];
      e0 += w.x * za.x + w.y * zb.x + w.z * zc.x + w.w * zd.x;
      e1 += w.x * za.y + w.y * zb.y + w.z * zc.y + w.w * zd.y;
      e2 += w.x * za.z + w.y * zb.z + w.z * zc.z + w.w * zd.z;
      e3 += w.x * za.w + w.y * zb.w + w.z * zc.w + w.w * zd.w;
    }
#pragma unroll
    for (int m = 4; m > 0; m >>= 1) {
      e0 += __shfl_xor(e0, m, 8);
      e1 += __shfl_xor(e1, m, 8);
      e2 += __shfl_xor(e2, m, 8);
      e3 += __shfl_xor(e3, m, 8);
    }
    if (p == 0) {
      float sb = h2_b[c];
      w_hcl[0 * NCLS + c] = sigmoidf_(0.01f * (e0 + sb));
      w_hcl[1 * NCLS + c] = sigmoidf_(0.01f * (e1 + sb));
      w_hcl[2 * NCLS + c] = sigmoidf_(0.01f * (e2 + sb));
      w_hcl[3 * NCLS + c] = sigmoidf_(0.01f * (e3 + sb));
    }
  }
}

// ---------------- Kernel 3: neighbour convolution + output ----------------
// 4 lanes per point n (i-quarters); each lane handles ALL 4 batches.
// Lane (t&3)=q covers latent i = q*4..q*4+3. dec_w row fetch: the 4 lanes of a
// group read 4 consecutive float4 = one 64B line per (n,k) row.
__global__ __launch_bounds__(256) void k_conv(const int* __restrict__ nid,
                                              const float* __restrict__ nd,
                                              const int* __restrict__ labels,
                                              const float* __restrict__ dec_w,
                                              const float* __restrict__ dec_b,
                                              const float* __restrict__ Bp,
                                              const float* __restrict__ w_enc,
                                              const float* __restrict__ w_hcl,
                                              float* __restrict__ out) {
  __shared__ float s_enc[NB * LAT];
  __shared__ float s_hcl[NB * NCLS];
  int t = threadIdx.x;
  if (t < NB * LAT) s_enc[t] = w_enc[t];
  s_hcl[t] = w_hcl[t];
  __syncthreads();

  int gidx = blockIdx.x * 256 + t;       // = n*4 + q
  int n = gidx >> 2;
  int q = t & 3;
  if (n >= NPTS) return;

  // Coalesced quarter loads: lane reads float4 #gidx of nd / nid.
  float4 ndq = ((const float4*)nd)[gidx];
  int4   niq = ((const int4*)nid)[gidx];
  float dq0 = ndq.x * ndq.x, dq1 = ndq.y * ndq.y, dq2 = ndq.z * ndq.z, dq3 = ndq.w * ndq.w;

  // Assemble all 16 d2/nbr per lane via 4-lane butterfly (order is a per-lane
  // permutation of k, identical for d2 and nbr, and k-sums are order-free).
  float dA[16];
  int nA[16];
  dA[0] = dq0; dA[1] = dq1; dA[2] = dq2; dA[3] = dq3;
  nA[0] = niq.x; nA[1] = niq.y; nA[2] = niq.z; nA[3] = niq.w;
#pragma unroll
  for (int j = 0; j < 4; ++j) {
    dA[4 + j] = __shfl_xor(dA[j], 1, 4);
    nA[4 + j] = __shfl_xor(nA[j], 1, 4);
  }
#pragma unroll
  for (int j = 0; j < 8; ++j) {
    dA[8 + j] = __shfl_xor(dA[j], 2, 4);
    nA[8 + j] = __shfl_xor(nA[j], 2, 4);
  }

  float Bv = Bp[0];
  float inv0 = 1.0f / (4.0f * Bv * Bv);
  int lab = labels[n];

  // Per-batch invden for this lane's 4 latents (i = q*4 + j), and coef = enc/s.
  float ivd[4][4];
  float coef[4][4];
#pragma unroll
  for (int b = 0; b < 4; ++b) {
    float H = s_hcl[b * NCLS + lab];
    float base = 1.0f - 0.5f * H;
    float rb = __builtin_amdgcn_rcpf(base * base);   // rbase2 = base^-2
    float rb2 = rb * rb;
    float rb4 = rb2 * rb2;
    float rb8 = rb4 * rb4;
    float start = inv0;
    if (q & 1) start *= rb4;
    if (q & 2) start *= rb8;
    ivd[b][0] = start;
    ivd[b][1] = ivd[b][0] * rb;
    ivd[b][2] = ivd[b][1] * rb;
    ivd[b][3] = ivd[b][2] * rb;
#pragma unroll
    for (int j = 0; j < 4; ++j) {
      float s = 0.f;
#pragma unroll
      for (int k = 0; k < KNBR; ++k) {
        s += fmaxf(fmaf(-dA[k], ivd[b][j], 1.0f), 0.0f);
      }
      coef[b][j] = s_enc[b * LAT + q * 4 + j] * __builtin_amdgcn_rcpf(s);
    }
  }

  // Pass 2: one 64B row-line per (n,k), reused across all 4 batches.
  float acc[4] = {0.f, 0.f, 0.f, 0.f};
#pragma unroll
  for (int k = 0; k < KNBR; ++k) {
    float4 dw = ((const float4*)dec_w)[(size_t)nA[k] * 4 + q];
    float d2k = dA[k];
#pragma unroll
    for (int b = 0; b < 4; ++b) {
      float w0 = fmaxf(fmaf(-d2k, ivd[b][0], 1.0f), 0.0f);
      float w1 = fmaxf(fmaf(-d2k, ivd[b][1], 1.0f), 0.0f);
      float w2 = fmaxf(fmaf(-d2k, ivd[b][2], 1.0f), 0.0f);
      float w3 = fmaxf(fmaf(-d2k, ivd[b][3], 1.0f), 0.0f);
      float a = acc[b];
      a = fmaf(coef[b][0] * w0, dw.x, a);
      a = fmaf(coef[b][1] * w1, dw.y, a);
      a = fmaf(coef[b][2] * w2, dw.z, a);
      a = fmaf(coef[b][3] * w3, dw.w, a);
      acc[b] = a;
    }
  }

  // Reduce i-quarters across the 4-lane group while redistributing batches:
  // after 2 butterfly rounds lane q holds batch bmap = ((q&1)<<1)|((q&2)>>1).
  float tA = (q & 1) ? acc[0] : acc[2];
  float tB = (q & 1) ? acc[1] : acc[3];
  float rA = __shfl_xor(tA, 1, 4);
  float rB = __shfl_xor(tB, 1, 4);
  float u = (q & 1) ? (acc[2] + rA) : (acc[0] + rA);
  float v = (q & 1) ? (acc[3] + rB) : (acc[1] + rB);
  float tC = (q & 2) ? u : v;
  float rC = __shfl_xor(tC, 2, 4);
  float f = (q & 2) ? (v + rC) : (u + rC);
  int bmap = ((q & 1) << 1) | ((q & 2) >> 1);
  out[(size_t)bmap * NPTS + n] = f + dec_b[n];
}

extern "C" void kernel_launch(void* const* d_in, const int* in_sizes, int n_in,
                              void* d_out, int out_size, void* d_ws, size_t ws_size,
                              hipStream_t stream) {
  const float* x      = (const float*)d_in[0];
  const int*   nid    = (const int*)d_in[1];
  const float* nd     = (const float*)d_in[2];
  const int*   labels = (const int*)d_in[3];
  const float* enc1_w = (const float*)d_in[4];
  const float* enc1_b = (const float*)d_in[5];
  const float* enc2_w = (const float*)d_in[6];
  const float* enc2_b = (const float*)d_in[7];
  const float* dec_w  = (const float*)d_in[8];
  const float* dec_b  = (const float*)d_in[9];
  const float* h0_w   = (const float*)d_in[10];
  const float* h0_b   = (const float*)d_in[11];
  const float* h1_w   = (const float*)d_in[12];
  const float* h1_b   = (const float*)d_in[13];
  const float* h2_w   = (const float*)d_in[14];
  const float* h2_b   = (const float*)d_in[15];
  const float* Bp     = (const float*)d_in[16];
  float* out = (float*)d_out;
  float* ws  = (float*)d_ws;
  float* part  = ws;          // 200*16 = 3200 floats
  float* w_enc = ws + 3200;   // 64 floats
  float* w_hcl = ws + 3264;   // 256 floats

  k_enc1<<<800, 256, 0, stream>>>(x, enc1_w, part);
  k_mlp<<<1, 512, 0, stream>>>(part, enc1_b, enc2_w, enc2_b, h0_w, h0_b,
                               h1_w, h1_b, h2_w, h2_b, w_enc, w_hcl);
  k_conv<<<(NPTS * 4 + 255) / 256, 256, 0, stream>>>(nid, nd, labels, dec_w, dec_b,
                                                     Bp, w_enc, w_hcl, out);
}